// Round 1
// 683.453 us; speedup vs baseline: 1.1044x; 1.1044x over previous
//
#include <hip/hip_runtime.h>
#include <cstddef>

// ContextWindowAttention: B=8192 windows, N=49 tokens, C=128, H=4, D=32.
// v2: operand-swapped MFMAs everywhere a transpose helps, so every LDS write is a
// ds_write_b64 of 4 consecutive channels and every global store is a float4.
// LDS cut 48KB -> 32KB (buf0: Q -> per-wave P scratch -> Z; buf1: K -> Vt; V held in
// registers through softmax) => 4-5 blocks/CU instead of 3. Swapped QK^T makes the
// softmax reduction 16-in-lane + 2 shuffles. All f32->bf16 via compiler casts (cvt_pk).

#define MFMA16 __builtin_amdgcn_mfma_f32_16x16x32_bf16

typedef float f32x4 __attribute__((ext_vector_type(4)));
typedef __bf16 bf16x8 __attribute__((ext_vector_type(8)));
typedef __bf16 bf16x4 __attribute__((ext_vector_type(4)));
typedef __bf16 bf16x2 __attribute__((ext_vector_type(2)));

constexpr int NTOK = 49;
constexpr int CDIM = 128;
constexpr int NWIN = 1024;
constexpr int NB = 8192;
constexpr float SCALE_F = 0.17677669529663687f;  // 32^-0.5

// Swizzled byte offsets (16B blocks XORed with row bits -> spread banks).
__device__ __forceinline__ int sw128(int row, int col) {  // [rows][128] bf16
  return (row << 8) + ((((col >> 3) ^ row) & 15) << 4) + ((col & 7) << 1);
}
__device__ __forceinline__ int sw64(int row, int col) {  // [rows][64] bf16
  return (row << 7) + ((((col >> 3) ^ (row >> 1)) & 7) << 4) + ((col & 7) << 1);
}
// Per-wave P scratch: [64 m][32 n] bf16 (4KB), XOR swizzle for b128 reads.
__device__ __forceinline__ int swp(int m, int nl) {
  return (m << 6) + ((((nl >> 3) ^ (m >> 1)) & 3) << 4) + ((nl & 7) << 1);
}

// ---------------- prepack: weights -> bf16 B-fragment order, TRANSPOSED bias ----------------
// wFrag layout unchanged: [mat(4)][frag(32)][lane(64)][8] bf16, frag = nt*4+ks.
// Fragment element j of lane (q4,li): W[k = ks*32+q4*8+j][n = nt*16+li].
// wBiasT[h][n*49+m] = bias[h][m][n]  (transposed for the swapped-S layout).
__global__ void prepack_kernel(const float* __restrict__ Wq, const float* __restrict__ Wkv,
                               const float* __restrict__ Wp, const float* __restrict__ bias_table,
                               const int* __restrict__ rel_idx,
                               unsigned short* __restrict__ wFrag, float* __restrict__ wBiasT) {
  int t = blockIdx.x * 256 + threadIdx.x;  // 0..16383
  if (t < 8192) {
    const int mat = t >> 11;  // 0..3
    const int g = t & 2047;
    const int frag = g >> 6, lane = g & 63;
    const int nt = frag >> 2, ks = frag & 3;
    const int li = lane & 15, q4 = lane >> 4;
    const int n = nt * 16 + li;
    bf16x8 tmp;
#pragma unroll
    for (int j = 0; j < 8; ++j) {
      const int k = ks * 32 + q4 * 8 + j;
      float v;
      if (mat == 0) v = Wq[k * 128 + n];
      else if (mat == 1) v = Wkv[k * 256 + n];
      else if (mat == 2) v = Wkv[k * 256 + 128 + n];
      else v = Wp[k * 128 + n];
      tmp[j] = (__bf16)v;
    }
    *(bf16x8*)(wFrag + (size_t)t * 8) = tmp;
  } else {
    const int tb = t - 8192;
    if (tb < 2401) {           // tb = n*49 + m
      const int m = tb % 49, n = tb / 49;
      const int r = rel_idx[m * 49 + n];
#pragma unroll
      for (int h = 0; h < 4; ++h) wBiasT[h * 2401 + tb] = bias_table[r * 4 + h];
    }
  }
}

// maskT[w][n][m] = mask[w][m][n]
__global__ void maskT_kernel(const float* __restrict__ mask, float* __restrict__ maskT) {
  const int w = blockIdx.x;
  const float* src = mask + (size_t)w * 2401;
  float* dst = maskT + (size_t)w * 2401;
  for (int i = threadIdx.x; i < 2401; i += 256) {
    dst[i] = src[(i % 49) * 49 + (i / 49)];
  }
}

template <bool MASKT>
__global__ __launch_bounds__(256, 4) void attn_kernel(
    const float* __restrict__ x, const float* __restrict__ y, const float* __restrict__ maskp,
    const float* __restrict__ bq, const float* __restrict__ bkv, const float* __restrict__ bp,
    const unsigned short* __restrict__ wFrag, const float* __restrict__ wBiasT,
    float* __restrict__ out) {
  // buf0 @0     (16KB): Q[64][128] -> per-wave 4KB P scratch -> Z[64][128]
  // buf1 @16384 (16KB): K[64][128] -> Vt[128][64]
  __shared__ __align__(16) unsigned char lds[32768];
  const int tid = threadIdx.x;
  const int w = tid >> 6;
  const int lane = tid & 63;
  const int li = lane & 15;
  const int q4 = lane >> 4;
  const int b = blockIdx.x;
  const int mh = w >> 1;  // token-half (rows 32*mh..32*mh+31)
  const int nh = w & 1;   // channel-half (cols 64*nh..64*nh+63)

  // ---- Load A-fragments of X and Y (rows >= 49 zeroed) ----
  bf16x8 ax[2][4], ay[2][4];
#pragma unroll
  for (int t = 0; t < 2; ++t) {
    const int mrow = mh * 32 + t * 16 + li;
    const bool mv = mrow < NTOK;
    const float* xr = x + ((size_t)b * NTOK + (mv ? mrow : 0)) * CDIM;
    const float* yr = y + ((size_t)b * NTOK + (mv ? mrow : 0)) * CDIM;
#pragma unroll
    for (int ks = 0; ks < 4; ++ks) {
      const int c0 = ks * 32 + q4 * 8;
      float4 a0 = *(const float4*)(xr + c0);
      float4 a1 = *(const float4*)(xr + c0 + 4);
      float4 b0 = *(const float4*)(yr + c0);
      float4 b1 = *(const float4*)(yr + c0 + 4);
      if (!mv) {
        a0.x = a0.y = a0.z = a0.w = 0.f; a1.x = a1.y = a1.z = a1.w = 0.f;
        b0.x = b0.y = b0.z = b0.w = 0.f; b1.x = b1.y = b1.z = b1.w = 0.f;
      }
      bf16x8 ta, tb;
      ta[0] = (__bf16)a0.x; ta[1] = (__bf16)a0.y; ta[2] = (__bf16)a0.z; ta[3] = (__bf16)a0.w;
      ta[4] = (__bf16)a1.x; ta[5] = (__bf16)a1.y; ta[6] = (__bf16)a1.z; ta[7] = (__bf16)a1.w;
      tb[0] = (__bf16)b0.x; tb[1] = (__bf16)b0.y; tb[2] = (__bf16)b0.z; tb[3] = (__bf16)b0.w;
      tb[4] = (__bf16)b1.x; tb[5] = (__bf16)b1.y; tb[6] = (__bf16)b1.z; tb[7] = (__bf16)b1.w;
      ax[t][ks] = ta;
      ay[t][ks] = tb;
    }
  }

  const unsigned short* wq = wFrag + 0 * 16384 + nh * 8192;
  const unsigned short* wk = wFrag + 1 * 16384 + nh * 8192;
  const unsigned short* wv = wFrag + 2 * 16384 + nh * 8192;
  const unsigned short* wp = wFrag + 3 * 16384 + nh * 8192;

  // ---- Phase 1: Q,K projections SWAPPED (MFMA(W,X) = (XW)^T): lane holds 4
  // consecutive channels of one token -> single ds_write_b64 per tile. ----
#pragma unroll
  for (int ntl = 0; ntl < 4; ++ntl) {  // Q -> buf0
    bf16x8 wf[4];
#pragma unroll
    for (int ks = 0; ks < 4; ++ks) wf[ks] = *(const bf16x8*)(wq + (ntl * 4 + ks) * 512 + lane * 8);
    const int ch0 = nh * 64 + ntl * 16 + q4 * 4;
    const float4 b4 = *(const float4*)(bq + ch0);
#pragma unroll
    for (int t = 0; t < 2; ++t) {
      f32x4 acc = {0.f, 0.f, 0.f, 0.f};
#pragma unroll
      for (int ks = 0; ks < 4; ++ks) acc = MFMA16(wf[ks], ax[t][ks], acc, 0, 0, 0);
      const int tok = mh * 32 + t * 16 + li;
      bf16x4 pv;
      pv[0] = (__bf16)(acc[0] + b4.x); pv[1] = (__bf16)(acc[1] + b4.y);
      pv[2] = (__bf16)(acc[2] + b4.z); pv[3] = (__bf16)(acc[3] + b4.w);
      *(bf16x4*)(lds + sw128(tok, ch0)) = pv;
    }
  }
#pragma unroll
  for (int ntl = 0; ntl < 4; ++ntl) {  // K -> buf1
    bf16x8 wf[4];
#pragma unroll
    for (int ks = 0; ks < 4; ++ks) wf[ks] = *(const bf16x8*)(wk + (ntl * 4 + ks) * 512 + lane * 8);
    const int ch0 = nh * 64 + ntl * 16 + q4 * 4;
    const float4 b4 = *(const float4*)(bkv + ch0);
#pragma unroll
    for (int t = 0; t < 2; ++t) {
      f32x4 acc = {0.f, 0.f, 0.f, 0.f};
#pragma unroll
      for (int ks = 0; ks < 4; ++ks) acc = MFMA16(wf[ks], ay[t][ks], acc, 0, 0, 0);
      const int tok = mh * 32 + t * 16 + li;
      bf16x4 pv;
      pv[0] = (__bf16)(acc[0] + b4.x); pv[1] = (__bf16)(acc[1] + b4.y);
      pv[2] = (__bf16)(acc[2] + b4.z); pv[3] = (__bf16)(acc[3] + b4.w);
      *(bf16x4*)(lds + 16384 + sw128(tok, ch0)) = pv;
    }
  }
  // V projection UNSWAPPED (lane holds 4 consecutive tokens of one channel ->
  // packs to 2x b32 in the transposed Vt layout). Kept in registers until buf1 frees.
  bf16x2 vpk[2][4][2];
#pragma unroll
  for (int ntl = 0; ntl < 4; ++ntl) {
    bf16x8 wf[4];
#pragma unroll
    for (int ks = 0; ks < 4; ++ks) wf[ks] = *(const bf16x8*)(wv + (ntl * 4 + ks) * 512 + lane * 8);
    const int nV = nh * 64 + ntl * 16 + li;
    const float bvv = bkv[128 + nV];
#pragma unroll
    for (int t = 0; t < 2; ++t) {
      f32x4 acc = {0.f, 0.f, 0.f, 0.f};
#pragma unroll
      for (int ks = 0; ks < 4; ++ks) acc = MFMA16(ay[t][ks], wf[ks], acc, 0, 0, 0);
      vpk[t][ntl][0][0] = (__bf16)(acc[0] + bvv);
      vpk[t][ntl][0][1] = (__bf16)(acc[1] + bvv);
      vpk[t][ntl][1][0] = (__bf16)(acc[2] + bvv);
      vpk[t][ntl][1][1] = (__bf16)(acc[3] + bvv);
    }
  }
  __syncthreads();  // #1: Q,K ready

  // ---- Phase 2a: wave = head. S^T = MFMA(K,Q): row n = nt*16+q4*4+r, col m = mt*16+li.
  const int h = w;
  f32x4 s[4][4];  // s[nt][mt]
  {
    bf16x8 aqf[4], bkf[4];
#pragma unroll
    for (int mt = 0; mt < 4; ++mt)
      aqf[mt] = *(const bf16x8*)(lds + sw128(mt * 16 + li, h * 32 + q4 * 8));
#pragma unroll
    for (int nt = 0; nt < 4; ++nt)
      bkf[nt] = *(const bf16x8*)(lds + 16384 + sw128(nt * 16 + li, h * 32 + q4 * 8));
    const f32x4 zz = {0.f, 0.f, 0.f, 0.f};
#pragma unroll
    for (int nt = 0; nt < 4; ++nt)
#pragma unroll
      for (int mt = 0; mt < 4; ++mt) s[nt][mt] = MFMA16(bkf[nt], aqf[mt], zz, 0, 0, 0);
  }
  __syncthreads();  // #2: all Q/K LDS reads done -> buf0/buf1 reusable

  // Vt writes into buf1 (overlaps the softmax VALU below)
  unsigned char* const pbase = lds + w * 4096;
#pragma unroll
  for (int ntl = 0; ntl < 4; ++ntl) {
    const int nV = nh * 64 + ntl * 16 + li;
#pragma unroll
    for (int t = 0; t < 2; ++t) {
      const int m0 = mh * 32 + t * 16 + q4 * 4;
      *(bf16x2*)(lds + 16384 + sw64(nV, m0)) = vpk[t][ntl][0];
      *(bf16x2*)(lds + 16384 + sw64(nV, m0 + 2)) = vpk[t][ntl][1];
    }
  }

  // Softmax over n: 16 values in-lane + 2 shuffles. Normalization deferred to after PV.
  const float* __restrict__ maskw = maskp + (size_t)(b & (NWIN - 1)) * 2401;
  const float* __restrict__ biash = wBiasT + h * 2401;
  float inv[4];
  bf16x2 pP[4][4][2];  // unnormalized exp, packed bf16 pairs [nt][mt][pair]
#pragma unroll
  for (int mt = 0; mt < 4; ++mt) {
    const int m = mt * 16 + li;
    const int mm = m < NTOK ? m : 0;
    float vv[4][4];
#pragma unroll
    for (int nt = 0; nt < 4; ++nt)
#pragma unroll
      for (int r = 0; r < 4; ++r) {
        const int n = nt * 16 + q4 * 4 + r;
        float tv = SCALE_F * s[nt][mt][r];
        if (n < NTOK) {
          if (MASKT) tv += biash[n * 49 + mm] + maskw[n * 49 + mm];
          else       tv += biash[n * 49 + mm] + maskw[mm * 49 + n];
        } else {
          tv = -1e30f;  // pad rows excluded
        }
        vv[nt][r] = tv;
      }
    float mx = vv[0][0];
#pragma unroll
    for (int nt = 0; nt < 4; ++nt)
#pragma unroll
      for (int r = 0; r < 4; ++r) mx = fmaxf(mx, vv[nt][r]);
    mx = fmaxf(mx, __shfl_xor(mx, 16));
    mx = fmaxf(mx, __shfl_xor(mx, 32));
    float sm = 0.f;
#pragma unroll
    for (int nt = 0; nt < 4; ++nt)
#pragma unroll
      for (int r = 0; r < 4; ++r) {
        const float e = __expf(vv[nt][r] - mx);
        vv[nt][r] = e;
        sm += e;
      }
    sm += __shfl_xor(sm, 16);
    sm += __shfl_xor(sm, 32);
    inv[mt] = __builtin_amdgcn_rcpf(sm);
#pragma unroll
    for (int nt = 0; nt < 4; ++nt) {
      pP[nt][mt][0][0] = (__bf16)vv[nt][0];
      pP[nt][mt][0][1] = (__bf16)vv[nt][1];
      pP[nt][mt][1][0] = (__bf16)vv[nt][2];
      pP[nt][mt][1][1] = (__bf16)vv[nt][3];
    }
  }
  // P chunk 0 (n 0..31) into this wave's private 4KB scratch (b64 writes, 4 consecutive n)
#pragma unroll
  for (int nt = 0; nt < 2; ++nt)
#pragma unroll
    for (int mt = 0; mt < 4; ++mt) {
      bf16x4 pv;
      pv[0] = pP[nt][mt][0][0]; pv[1] = pP[nt][mt][0][1];
      pv[2] = pP[nt][mt][1][0]; pv[3] = pP[nt][mt][1][1];
      *(bf16x4*)(pbase + swp(mt * 16 + li, nt * 16 + q4 * 4)) = pv;
    }
  __syncthreads();  // #3: Vt ready

  // ---- Phase 2b: O^T = MFMA(V^T, P), K-dim chunked 2x32 through the 4KB scratch ----
  bf16x8 bv2[2][2];
#pragma unroll
  for (int cht = 0; cht < 2; ++cht)
#pragma unroll
    for (int ksn = 0; ksn < 2; ++ksn)
      bv2[cht][ksn] =
          *(const bf16x8*)(lds + 16384 + sw64(h * 32 + cht * 16 + li, ksn * 32 + q4 * 8));
  f32x4 o[2][4];
  {
    bf16x8 ap[4];
#pragma unroll
    for (int mt = 0; mt < 4; ++mt)
      ap[mt] = *(const bf16x8*)(pbase + swp(mt * 16 + li, q4 * 8));
    const f32x4 zz = {0.f, 0.f, 0.f, 0.f};
#pragma unroll
    for (int cht = 0; cht < 2; ++cht)
#pragma unroll
      for (int mt = 0; mt < 4; ++mt) o[cht][mt] = MFMA16(bv2[cht][0], ap[mt], zz, 0, 0, 0);
    // overwrite scratch with chunk 1 (same-wave in-order DS makes the WAR safe)
#pragma unroll
    for (int nt = 0; nt < 2; ++nt)
#pragma unroll
      for (int mt = 0; mt < 4; ++mt) {
        bf16x4 pv;
        pv[0] = pP[2 + nt][mt][0][0]; pv[1] = pP[2 + nt][mt][0][1];
        pv[2] = pP[2 + nt][mt][1][0]; pv[3] = pP[2 + nt][mt][1][1];
        *(bf16x4*)(pbase + swp(mt * 16 + li, nt * 16 + q4 * 4)) = pv;
      }
#pragma unroll
    for (int mt = 0; mt < 4; ++mt)
      ap[mt] = *(const bf16x8*)(pbase + swp(mt * 16 + li, q4 * 8));
#pragma unroll
    for (int cht = 0; cht < 2; ++cht)
#pragma unroll
      for (int mt = 0; mt < 4; ++mt)
        o[cht][mt] = MFMA16(bv2[cht][1], ap[mt], o[cht][mt], 0, 0, 0);
  }
  __syncthreads();  // #4: all PV reads done -> buf0 reusable for Z

  // Z[tok][chan] (deferred softmax normalization applied here; inv is per-col m = li ✓)
#pragma unroll
  for (int cht = 0; cht < 2; ++cht)
#pragma unroll
    for (int mt = 0; mt < 4; ++mt) {
      bf16x4 zv;
      zv[0] = (__bf16)(o[cht][mt][0] * inv[mt]);
      zv[1] = (__bf16)(o[cht][mt][1] * inv[mt]);
      zv[2] = (__bf16)(o[cht][mt][2] * inv[mt]);
      zv[3] = (__bf16)(o[cht][mt][3] * inv[mt]);
      *(bf16x4*)(lds + sw128(mt * 16 + li, h * 32 + cht * 16 + q4 * 4)) = zv;
    }
  __syncthreads();  // #5: Z ready

  // ---- Phase 3: out = Z @ Wp + bp, SWAPPED -> float4 stores ----
  bf16x8 az[2][4];
#pragma unroll
  for (int t = 0; t < 2; ++t)
#pragma unroll
    for (int ks = 0; ks < 4; ++ks)
      az[t][ks] = *(const bf16x8*)(lds + sw128(mh * 32 + t * 16 + li, ks * 32 + q4 * 8));
#pragma unroll
  for (int ntl = 0; ntl < 4; ++ntl) {
    bf16x8 wf[4];
#pragma unroll
    for (int ks = 0; ks < 4; ++ks) wf[ks] = *(const bf16x8*)(wp + (ntl * 4 + ks) * 512 + lane * 8);
    const int ch0 = nh * 64 + ntl * 16 + q4 * 4;
    const float4 b4 = *(const float4*)(bp + ch0);
#pragma unroll
    for (int t = 0; t < 2; ++t) {
      f32x4 acc = {0.f, 0.f, 0.f, 0.f};
#pragma unroll
      for (int ks = 0; ks < 4; ++ks) acc = MFMA16(wf[ks], az[t][ks], acc, 0, 0, 0);
      const int tok = mh * 32 + t * 16 + li;
      if (tok < NTOK) {
        float4 st;
        st.x = acc[0] + b4.x; st.y = acc[1] + b4.y;
        st.z = acc[2] + b4.z; st.w = acc[3] + b4.w;
        *(float4*)(out + ((size_t)b * NTOK + tok) * CDIM + ch0) = st;
      }
    }
  }
}

extern "C" void kernel_launch(void* const* d_in, const int* in_sizes, int n_in, void* d_out,
                              int out_size, void* d_ws, size_t ws_size, hipStream_t stream) {
  const float* x = (const float*)d_in[0];
  const float* y = (const float*)d_in[1];
  const float* mask = (const float*)d_in[2];
  const float* Wq = (const float*)d_in[3];
  const float* bq = (const float*)d_in[4];
  const float* Wkv = (const float*)d_in[5];
  const float* bkv = (const float*)d_in[6];
  const float* bt = (const float*)d_in[7];
  const float* Wp = (const float*)d_in[8];
  const float* bp = (const float*)d_in[9];
  const int* rel = (const int*)d_in[10];
  float* out = (float*)d_out;

  // ws: 128KB fragment-ordered weights + [H][49][49] transposed bias + (optional) maskT
  unsigned short* wFrag = (unsigned short*)d_ws;
  float* wBiasT = (float*)((char*)d_ws + 131072);
  float* maskT = (float*)((char*)d_ws + 196608);
  const size_t needT = 196608 + (size_t)NWIN * 2401 * sizeof(float);

  prepack_kernel<<<64, 256, 0, stream>>>(Wq, Wkv, Wp, bt, rel, wFrag, wBiasT);
  if (ws_size >= needT) {
    maskT_kernel<<<NWIN, 256, 0, stream>>>(mask, maskT);
    attn_kernel<true><<<NB, 256, 0, stream>>>(x, y, maskT, bq, bkv, bp, wFrag, wBiasT, out);
  } else {
    // fallback: read mask transposed directly (uncoalesced but correct)
    attn_kernel<false><<<NB, 256, 0, stream>>>(x, y, mask, bq, bkv, bp, wFrag, wBiasT, out);
  }
}